// Round 4
// baseline (314.000 us; speedup 1.0000x reference)
//
#include <hip/hip_runtime.h>
#include <math.h>

#define NPTS 512
#define CH   128
#define NB   2
#define KVAL 460   // int(512 * (1 - 0.1))

typedef __attribute__((ext_vector_type(8))) short short8;
typedef __attribute__((ext_vector_type(4))) float f32x4;

union S8U { short8 s8; unsigned u[4]; };

__device__ __forceinline__ unsigned short f2bf_rne(float f) {
    unsigned int u = __float_as_uint(f);
    u += 0x7fffu + ((u >> 16) & 1u);
    return (unsigned short)(u >> 16);
}
// pack two f32 -> {bf16(a) lo, bf16(b) hi} by truncation: one v_perm_b32
__device__ __forceinline__ unsigned pk_trunc(float a, float b) {
    return __builtin_amdgcn_perm(__float_as_uint(b), __float_as_uint(a), 0x07060302u);
}
__device__ __forceinline__ float bf_lo(unsigned u) { return __uint_as_float(u << 16); }
__device__ __forceinline__ float bf_hi(unsigned u) { return __uint_as_float(u & 0xffff0000u); }

// Block = 16i x 32j tile (grid 1024 = 4 blocks/CU). 4 waves: h = wave&1 picks the
// i-row within a 2-row chunk, g = wave>>1 picks the output-channel half.
// j-tile stays 32 wide so ALL global stores are full 128B lines (round-3 lesson:
// 64B half-line stores from different XCDs caused 10x write amplification).
// vj rows live in registers (2 rows/lane, bf16-packed); W1/W2 B-frags with BN
// scales folded live in AGPRs. LDS ~26.4 KB.
__global__ __launch_bounds__(256, 3)
void mlp_mfma_kernel(const float* __restrict__ vp, const float* __restrict__ ep,
                     const float* __restrict__ W1,
                     const float* __restrict__ g1, const float* __restrict__ be1,
                     const float* __restrict__ m1, const float* __restrict__ v1,
                     const float* __restrict__ W2,
                     const float* __restrict__ g2, const float* __restrict__ be2,
                     const float* __restrict__ m2, const float* __restrict__ v2,
                     const float* __restrict__ W3, const float* __restrict__ b3,
                     float* __restrict__ ep_out, float* __restrict__ ns_out)
{
    __shared__ __align__(16) float    sVI[16*132];   //  8,448 B
    __shared__ __align__(16) unsigned sH1[64*68];    // 17,408 B u32 = 2 bf16 ch (stride 68 u32)
    __shared__ float sPart[2][64];                   //    512 B

    const int t    = threadIdx.x;
    const int lane = t & 63;
    const int w    = t >> 6;
    const int h    = w & 1;
    const int g    = w >> 1;
    const int l15  = lane & 15;
    const int q    = lane >> 4;
    const int q8   = q * 8;
    const int b    = blockIdx.z;
    const int i0   = blockIdx.y * 16;
    const int j0   = blockIdx.x * 32;

    // ---- stage vp i-rows in fp32 (coalesced float4) ----
    for (int k = 0; k < 2; ++k) {
        int idx = k*256 + t;
        int r = idx >> 5, c4 = (idx & 31) * 4;
        *(float4*)&sVI[r*132 + c4] = *(const float4*)&vp[((size_t)(b*NPTS + i0 + r))*CH + c4];
    }

    // ---- vj rows for this lane (ms=0: j0+l15, ms=1: j0+16+l15), bf16-packed ----
    unsigned vjp[2][4][4];
    #pragma unroll
    for (int ms = 0; ms < 2; ++ms) {
        #pragma unroll
        for (int kt = 0; kt < 4; ++kt) {
            const float* p = &vp[((size_t)(b*NPTS + j0 + ms*16 + l15))*CH + kt*32 + q8];
            float4 x0 = *(const float4*)p;
            float4 x1 = *(const float4*)(p + 4);
            vjp[ms][kt][0] = (unsigned)f2bf_rne(x0.x) | ((unsigned)f2bf_rne(x0.y) << 16);
            vjp[ms][kt][1] = (unsigned)f2bf_rne(x0.z) | ((unsigned)f2bf_rne(x0.w) << 16);
            vjp[ms][kt][2] = (unsigned)f2bf_rne(x1.x) | ((unsigned)f2bf_rne(x1.y) << 16);
            vjp[ms][kt][3] = (unsigned)f2bf_rne(x1.z) | ((unsigned)f2bf_rne(x1.w) << 16);
        }
    }

    // ---- W1 bf16 B-frags, BN1 scale folded ----
    short8 w1f[4][4];
    float  t1v[4];
    #pragma unroll
    for (int nt = 0; nt < 4; ++nt) {
        int o = g*64 + nt*16 + l15;
        float s = g1[o] * rsqrtf(v1[o] + 1e-5f);
        t1v[nt] = be1[o] - m1[o]*s;
        #pragma unroll
        for (int kt = 0; kt < 4; ++kt) {
            const float* p = &W1[(size_t)o*CH + kt*32 + q8];
            float4 x0 = *(const float4*)p;
            float4 x1 = *(const float4*)(p + 4);
            S8U u;
            u.u[0] = (unsigned)f2bf_rne(x0.x*s) | ((unsigned)f2bf_rne(x0.y*s) << 16);
            u.u[1] = (unsigned)f2bf_rne(x0.z*s) | ((unsigned)f2bf_rne(x0.w*s) << 16);
            u.u[2] = (unsigned)f2bf_rne(x1.x*s) | ((unsigned)f2bf_rne(x1.y*s) << 16);
            u.u[3] = (unsigned)f2bf_rne(x1.z*s) | ((unsigned)f2bf_rne(x1.w*s) << 16);
            w1f[nt][kt] = u.s8;
        }
    }
    // ---- W2 bf16 B-frags, BN2 folded ----
    short8 w2f[2][4];
    float  t2v[2], w3v[2];
    #pragma unroll
    for (int nt = 0; nt < 2; ++nt) {
        int o = g*32 + nt*16 + l15;
        float s = g2[o] * rsqrtf(v2[o] + 1e-5f);
        t2v[nt] = be2[o] - m2[o]*s;
        w3v[nt] = W3[o];
        #pragma unroll
        for (int kt = 0; kt < 4; ++kt) {
            const float* p = &W2[(size_t)o*CH + kt*32 + q8];
            float4 x0 = *(const float4*)p;
            float4 x1 = *(const float4*)(p + 4);
            S8U u;
            u.u[0] = (unsigned)f2bf_rne(x0.x*s) | ((unsigned)f2bf_rne(x0.y*s) << 16);
            u.u[1] = (unsigned)f2bf_rne(x0.z*s) | ((unsigned)f2bf_rne(x0.w*s) << 16);
            u.u[2] = (unsigned)f2bf_rne(x1.x*s) | ((unsigned)f2bf_rne(x1.y*s) << 16);
            u.u[3] = (unsigned)f2bf_rne(x1.z*s) | ((unsigned)f2bf_rne(x1.w*s) << 16);
            w2f[nt][kt] = u.s8;
        }
    }
    const float b3v = b3[0];
    __syncthreads();

    // ---- 8 chunks of 2 i-rows x 32 j = 64 pairs ----
    #pragma unroll 1
    for (int ch = 0; ch < 8; ++ch) {
        const int iirow = ch*2 + h;

        // ===== layer 1: A-frags (d^2) in MFMA layout; ns for free (fp32) =====
        #pragma unroll
        for (int ms = 0; ms < 2; ++ms) {
            short8 afr[4];
            float ns = 0.f;
            #pragma unroll
            for (int kt = 0; kt < 4; ++kt) {
                const float* vi = &sVI[iirow*132 + kt*32 + q8];   // wave-uniform broadcast
                float4 a0 = *(const float4*)vi, a1 = *(const float4*)(vi + 4);
                float c0 = bf_lo(vjp[ms][kt][0]), c1 = bf_hi(vjp[ms][kt][0]);
                float c2 = bf_lo(vjp[ms][kt][1]), c3 = bf_hi(vjp[ms][kt][1]);
                float c4 = bf_lo(vjp[ms][kt][2]), c5 = bf_hi(vjp[ms][kt][2]);
                float c6 = bf_lo(vjp[ms][kt][3]), c7 = bf_hi(vjp[ms][kt][3]);
                float d0 = a0.x - c0, d1 = a0.y - c1, d2 = a0.z - c2, d3 = a0.w - c3;
                float d4 = a1.x - c4, d5 = a1.y - c5, d6 = a1.z - c6, d7 = a1.w - c7;
                float p0 = d0*d0, p1 = d1*d1, p2 = d2*d2, p3 = d3*d3;
                float p4 = d4*d4, p5 = d5*d5, p6 = d6*d6, p7 = d7*d7;
                ns += ((p0 + p1) + (p2 + p3)) + ((p4 + p5) + (p6 + p7));
                S8U u;
                u.u[0] = pk_trunc(p0, p1);
                u.u[1] = pk_trunc(p2, p3);
                u.u[2] = pk_trunc(p4, p5);
                u.u[3] = pk_trunc(p6, p7);
                afr[kt] = u.s8;
            }
            ns += __shfl_xor(ns, 16);
            ns += __shfl_xor(ns, 32);
            if (g == 0 && lane < 16) {   // two 64B halves from same wave -> full line
                ns_out[((size_t)(b*NPTS + i0 + iirow))*NPTS + j0 + ms*16 + lane] = -ns;
            }

            #pragma unroll
            for (int nt = 0; nt < 4; ++nt) {
                f32x4 acc = {0.f, 0.f, 0.f, 0.f};
                acc = __builtin_amdgcn_mfma_f32_16x16x32_bf16(afr[0], w1f[nt][0], acc, 0, 0, 0);
                acc = __builtin_amdgcn_mfma_f32_16x16x32_bf16(afr[1], w1f[nt][1], acc, 0, 0, 0);
                acc = __builtin_amdgcn_mfma_f32_16x16x32_bf16(afr[2], w1f[nt][2], acc, 0, 0, 0);
                acc = __builtin_amdgcn_mfma_f32_16x16x32_bf16(afr[3], w1f[nt][3], acc, 0, 0, 0);
                float hv0 = acc[0] + t1v[nt]; hv0 = hv0 > 0.f ? hv0 : hv0*0.01f;
                float hv1 = acc[1] + t1v[nt]; hv1 = hv1 > 0.f ? hv1 : hv1*0.01f;
                float hv2 = acc[2] + t1v[nt]; hv2 = hv2 > 0.f ? hv2 : hv2*0.01f;
                float hv3 = acc[3] + t1v[nt]; hv3 = hv3 > 0.f ? hv3 : hv3*0.01f;
                // pair channels (o even, o+1) via xor-1 exchange -> 2 x ds_write_b32
                float ov0 = __shfl_xor(hv0, 1);
                float ov1 = __shfl_xor(hv1, 1);
                float ov2 = __shfl_xor(hv2, 1);
                float ov3 = __shfl_xor(hv3, 1);
                bool odd = (l15 & 1);
                float lo0 = odd ? ov2 : hv0,  hi0 = odd ? hv2 : ov0;
                float lo1 = odd ? ov3 : hv1,  hi1 = odd ? hv3 : ov1;
                unsigned w0 = pk_trunc(lo0, hi0);
                unsigned w1 = pk_trunc(lo1, hi1);
                int col = g*32 + nt*8 + (l15 >> 1);
                int row = h*32 + ms*16 + q*4 + (odd ? 2 : 0);
                sH1[row*68 + col]     = w0;
                sH1[(row+1)*68 + col] = w1;
            }
        }
        __syncthreads();

        // ===== layer 2 (+BN fold) + layer 3 dot =====
        #pragma unroll
        for (int s = 0; s < 2; ++s) {
            short8 hfr[4];
            #pragma unroll
            for (int kt = 0; kt < 4; ++kt)
                hfr[kt] = *(const short8*)&sH1[(h*32 + s*16 + l15)*68 + kt*16 + q*4];

            float part[4] = {0.f, 0.f, 0.f, 0.f};
            #pragma unroll
            for (int nt = 0; nt < 2; ++nt) {
                f32x4 acc = {0.f, 0.f, 0.f, 0.f};
                acc = __builtin_amdgcn_mfma_f32_16x16x32_bf16(hfr[0], w2f[nt][0], acc, 0, 0, 0);
                acc = __builtin_amdgcn_mfma_f32_16x16x32_bf16(hfr[1], w2f[nt][1], acc, 0, 0, 0);
                acc = __builtin_amdgcn_mfma_f32_16x16x32_bf16(hfr[2], w2f[nt][2], acc, 0, 0, 0);
                acc = __builtin_amdgcn_mfma_f32_16x16x32_bf16(hfr[3], w2f[nt][3], acc, 0, 0, 0);
                #pragma unroll
                for (int r = 0; r < 4; ++r) {
                    float hv = acc[r] + t2v[nt];
                    hv = hv > 0.f ? hv : hv*0.01f;
                    part[r] = fmaf(hv, w3v[nt], part[r]);
                }
            }
            #pragma unroll
            for (int r = 0; r < 4; ++r) {
                part[r] += __shfl_xor(part[r], 1);
                part[r] += __shfl_xor(part[r], 2);
                part[r] += __shfl_xor(part[r], 4);
                part[r] += __shfl_xor(part[r], 8);
            }
            if (l15 == 0) {
                #pragma unroll
                for (int r = 0; r < 4; ++r)
                    sPart[g][h*32 + s*16 + q*4 + r] = part[r];
            }
        }
        __syncthreads();

        // ===== epilogue: 64 pairs (2 full 128B rows) -> sigmoid * ep_last =====
        if (t < 64) {
            float logit = sPart[0][t] + sPart[1][t] + b3v;
            float sg = 1.f / (1.f + __expf(-logit));
            int i = i0 + ch*2 + (t >> 5);
            int j = j0 + (t & 31);
            float epl = (i == j) ? 0.f : ep[((size_t)(b*NPTS + i))*NPTS + j];
            ep_out[((size_t)(b*NPTS + i))*NPTS + j] = sg * epl;
        }
        // sH1/sPart rewrites for chunk ch+1 are fenced by the barrier pair above.
    }
}

// ---- kernel 2: per-row top-k mask + L1 renorm + diag + row norm, in place ----
__device__ __forceinline__ float block_reduce_sum(float v, float* red) {
    #pragma unroll
    for (int off = 32; off; off >>= 1) v += __shfl_down(v, off);
    int wid = threadIdx.x >> 6;
    if ((threadIdx.x & 63) == 0) red[wid] = v;
    __syncthreads();
    float s = red[0] + red[1] + red[2] + red[3];
    __syncthreads();
    return s;
}

__global__ __launch_bounds__(256)
void topk_norm_kernel(const float* __restrict__ ep_gen, float* __restrict__ ep_io) {
    __shared__ __align__(16) float r[NPTS];
    __shared__ float red[4];
    const int row = blockIdx.x;          // b*512 + i
    const int i   = row & (NPTS - 1);
    const int t   = threadIdx.x;
    const float* gen = &ep_gen[(size_t)row * NPTS];
    float* io        = &ep_io [(size_t)row * NPTS];

    float v0 = io[t], v1 = io[t + 256];
    r[t] = v0; r[t + 256] = v1;
    float g0 = (t       == i) ? 0.f : gen[t];
    float g1 = (t + 256 == i) ? 0.f : gen[t + 256];
    __syncthreads();

    float s_last = block_reduce_sum(g0 + g1, red);

    // rank by strict-greater count. Values are sigmoid*uniform: exact float
    // ties are measure-zero, so lax.top_k's index tiebreak can't change the set.
    int c0 = 0, c1 = 0;
    #pragma unroll 4
    for (int k = 0; k < NPTS; k += 4) {
        float4 rv = *(const float4*)&r[k];
        c0 += (rv.x > v0) + (rv.y > v0) + (rv.z > v0) + (rv.w > v0);
        c1 += (rv.x > v1) + (rv.y > v1) + (rv.z > v1) + (rv.w > v1);
    }
    float m0 = (c0 < KVAL) ? v0 : 0.f;
    float m1 = (c1 < KVAL) ? v1 : 0.f;

    float l1 = block_reduce_sum(m0 + m1, red);
    l1 = fmaxf(l1, 1e-12f);
    float scale = s_last / l1;
    float f0 = m0*scale + ((t       == i) ? 1.f : 0.f) + 1e-6f;
    float f1 = m1*scale + ((t + 256 == i) ? 1.f : 0.f) + 1e-6f;

    float s2 = block_reduce_sum(f0 + f1, red);
    float inv = 1.f / s2;
    io[t]       = f0 * inv;
    io[t + 256] = f1 * inv;
}

extern "C" void kernel_launch(void* const* d_in, const int* in_sizes, int n_in,
                              void* d_out, int out_size, void* d_ws, size_t ws_size,
                              hipStream_t stream) {
    const float* vp  = (const float*)d_in[0];
    const float* ep  = (const float*)d_in[1];
    const float* W1  = (const float*)d_in[2];
    const float* g1  = (const float*)d_in[3];
    const float* be1 = (const float*)d_in[4];
    const float* m1  = (const float*)d_in[5];
    const float* v1  = (const float*)d_in[6];
    const float* W2  = (const float*)d_in[7];
    const float* g2  = (const float*)d_in[8];
    const float* be2 = (const float*)d_in[9];
    const float* m2  = (const float*)d_in[10];
    const float* v2  = (const float*)d_in[11];
    const float* W3  = (const float*)d_in[12];
    const float* b3  = (const float*)d_in[13];

    float* out    = (float*)d_out;
    float* ep_out = out;                          // [2,512,512]
    float* ns_out = out + (size_t)NB*NPTS*NPTS;   // [2,512,512]

    dim3 grid(NPTS/32, NPTS/16, NB);              // 1024 blocks, j-tiles 128B wide
    mlp_mfma_kernel<<<grid, dim3(256), 0, stream>>>(vp, ep, W1, g1, be1, m1, v1,
                                                    W2, g2, be2, m2, v2, W3, b3,
                                                    ep_out, ns_out);
    topk_norm_kernel<<<dim3(NB*NPTS), dim3(256), 0, stream>>>(ep, ep_out);
}

// Round 5
// 181.425 us; speedup vs baseline: 1.7307x; 1.7307x over previous
//
#include <hip/hip_runtime.h>
#include <math.h>

#define NPTS 512
#define CH   128
#define NB   2
#define KVAL 460   // int(512 * (1 - 0.1))

typedef __attribute__((ext_vector_type(8))) short short8;
typedef __attribute__((ext_vector_type(4))) float f32x4;

union S8U { short8 s8; unsigned u[4]; uint4 u4; };

__device__ __forceinline__ unsigned short f2bf_rne(float f) {
    unsigned int u = __float_as_uint(f);
    u += 0x7fffu + ((u >> 16) & 1u);
    return (unsigned short)(u >> 16);
}
// pack two fp32 -> {bf16(a) lo, bf16(b) hi}, round-to-nearest-even
__device__ __forceinline__ unsigned pk_rne(float a, float b) {
    return ((unsigned)f2bf_rne(a)) | (((unsigned)f2bf_rne(b)) << 16);
}
// pack by truncation: one v_perm_b32 (used on d^2 values feeding MFMA only)
__device__ __forceinline__ unsigned pk_trunc(float a, float b) {
    return __builtin_amdgcn_perm(__float_as_uint(b), __float_as_uint(a), 0x07060302u);
}
__device__ __forceinline__ float bf_lo(unsigned u) { return __uint_as_float(u << 16); }
__device__ __forceinline__ float bf_hi(unsigned u) { return __uint_as_float(u & 0xffff0000u); }

// Block = 16i x 32j tile (grid 1024). 4 waves: h = wave&1 -> i-row within the
// 2-row chunk, g = wave>>1 -> output-channel half.
// Hard-won constraints baked in:
//  * j-tile = 32 (128B): full-line output stores (R3: 64B split lines across
//    XCDs caused 10x write amplification).
//  * vj stays in LDS + __launch_bounds__(256,2): R4 put vj rows in registers
//    under (256,3) -> allocator spill -> 284 MB scratch traffic.
//  * All LDS tiles bf16-packed: 31 KB total, residency is register-bound.
__global__ __launch_bounds__(256, 2)
void mlp_mfma_kernel(const float* __restrict__ vp, const float* __restrict__ ep,
                     const float* __restrict__ W1,
                     const float* __restrict__ g1, const float* __restrict__ be1,
                     const float* __restrict__ m1, const float* __restrict__ v1,
                     const float* __restrict__ W2,
                     const float* __restrict__ g2, const float* __restrict__ be2,
                     const float* __restrict__ m2, const float* __restrict__ v2,
                     const float* __restrict__ W3, const float* __restrict__ b3,
                     float* __restrict__ ep_out, float* __restrict__ ns_out)
{
    __shared__ __align__(16) unsigned sVI[16*68];   //  4,352 B  bf16x2 [row][ch/2]
    __shared__ __align__(16) unsigned sVJ[32*68];   //  8,704 B
    __shared__ __align__(16) unsigned sH1[64*68];   // 17,408 B  bf16x2 [m][o/2]
    __shared__ float sPart[2][64];                  //    512 B

    const int t    = threadIdx.x;
    const int lane = t & 63;
    const int w    = t >> 6;
    const int h    = w & 1;
    const int g    = w >> 1;
    const int l15  = lane & 15;
    const int q    = lane >> 4;
    const int q8   = q * 8;
    const int b    = blockIdx.z;
    const int i0   = blockIdx.y * 16;
    const int j0   = blockIdx.x * 32;

    // ---- stage vp tiles, coalesced float4 -> packed bf16 ----
    for (int k = 0; k < 2; ++k) {
        int idx = k*256 + t;
        int r = idx >> 5, c = idx & 31;
        float4 x = *(const float4*)&vp[((size_t)(b*NPTS + i0 + r))*CH + c*4];
        uint2 p; p.x = pk_rne(x.x, x.y); p.y = pk_rne(x.z, x.w);
        *(uint2*)&sVI[r*68 + c*2] = p;
    }
    for (int k = 0; k < 4; ++k) {
        int idx = k*256 + t;
        int r = idx >> 5, c = idx & 31;
        float4 x = *(const float4*)&vp[((size_t)(b*NPTS + j0 + r))*CH + c*4];
        uint2 p; p.x = pk_rne(x.x, x.y); p.y = pk_rne(x.z, x.w);
        *(uint2*)&sVJ[r*68 + c*2] = p;
    }

    // ---- W1 bf16 B-frags, BN1 scale folded (64 VGPRs) ----
    short8 w1f[4][4];
    float  t1v[4];
    #pragma unroll
    for (int nt = 0; nt < 4; ++nt) {
        int o = g*64 + nt*16 + l15;
        float s = g1[o] * rsqrtf(v1[o] + 1e-5f);
        t1v[nt] = be1[o] - m1[o]*s;
        #pragma unroll
        for (int kt = 0; kt < 4; ++kt) {
            const float* p = &W1[(size_t)o*CH + kt*32 + q8];
            float4 x0 = *(const float4*)p;
            float4 x1 = *(const float4*)(p + 4);
            S8U u;
            u.u[0] = pk_rne(x0.x*s, x0.y*s);
            u.u[1] = pk_rne(x0.z*s, x0.w*s);
            u.u[2] = pk_rne(x1.x*s, x1.y*s);
            u.u[3] = pk_rne(x1.z*s, x1.w*s);
            w1f[nt][kt] = u.s8;
        }
    }
    // ---- W2 bf16 B-frags, BN2 folded (32 VGPRs) ----
    short8 w2f[2][4];
    float  t2v[2], w3v[2];
    #pragma unroll
    for (int nt = 0; nt < 2; ++nt) {
        int o = g*32 + nt*16 + l15;
        float s = g2[o] * rsqrtf(v2[o] + 1e-5f);
        t2v[nt] = be2[o] - m2[o]*s;
        w3v[nt] = W3[o];
        #pragma unroll
        for (int kt = 0; kt < 4; ++kt) {
            const float* p = &W2[(size_t)o*CH + kt*32 + q8];
            float4 x0 = *(const float4*)p;
            float4 x1 = *(const float4*)(p + 4);
            S8U u;
            u.u[0] = pk_rne(x0.x*s, x0.y*s);
            u.u[1] = pk_rne(x0.z*s, x0.w*s);
            u.u[2] = pk_rne(x1.x*s, x1.y*s);
            u.u[3] = pk_rne(x1.z*s, x1.w*s);
            w2f[nt][kt] = u.s8;
        }
    }
    const float b3v = b3[0];
    __syncthreads();

    // ---- 8 chunks of 2 i-rows x 32 j = 64 pairs ----
    #pragma unroll 1
    for (int ch = 0; ch < 8; ++ch) {
        const int iirow = ch*2 + h;

        // ===== layer 1: A-frags (d^2) built in MFMA layout from packed LDS =====
        #pragma unroll
        for (int ms = 0; ms < 2; ++ms) {
            short8 afr[4];
            float ns = 0.f;
            #pragma unroll
            for (int kt = 0; kt < 4; ++kt) {
                uint4 av = *(const uint4*)&sVI[iirow*68 + kt*16 + q*4];          // broadcast
                uint4 cv = *(const uint4*)&sVJ[(ms*16 + l15)*68 + kt*16 + q*4];  // per-lane
                float d0 = bf_lo(av.x) - bf_lo(cv.x), d1 = bf_hi(av.x) - bf_hi(cv.x);
                float d2 = bf_lo(av.y) - bf_lo(cv.y), d3 = bf_hi(av.y) - bf_hi(cv.y);
                float d4 = bf_lo(av.z) - bf_lo(cv.z), d5 = bf_hi(av.z) - bf_hi(cv.z);
                float d6 = bf_lo(av.w) - bf_lo(cv.w), d7 = bf_hi(av.w) - bf_hi(cv.w);
                float p0 = d0*d0, p1 = d1*d1, p2 = d2*d2, p3 = d3*d3;
                float p4 = d4*d4, p5 = d5*d5, p6 = d6*d6, p7 = d7*d7;
                ns += ((p0 + p1) + (p2 + p3)) + ((p4 + p5) + (p6 + p7));
                S8U u;
                u.u[0] = pk_trunc(p0, p1);
                u.u[1] = pk_trunc(p2, p3);
                u.u[2] = pk_trunc(p4, p5);
                u.u[3] = pk_trunc(p6, p7);
                afr[kt] = u.s8;
            }
            ns += __shfl_xor(ns, 16);
            ns += __shfl_xor(ns, 32);
            if (g == 0 && lane < 16) {
                ns_out[((size_t)(b*NPTS + i0 + iirow))*NPTS + j0 + ms*16 + lane] = -ns;
            }

            #pragma unroll
            for (int nt = 0; nt < 4; ++nt) {
                f32x4 acc = {0.f, 0.f, 0.f, 0.f};
                acc = __builtin_amdgcn_mfma_f32_16x16x32_bf16(afr[0], w1f[nt][0], acc, 0, 0, 0);
                acc = __builtin_amdgcn_mfma_f32_16x16x32_bf16(afr[1], w1f[nt][1], acc, 0, 0, 0);
                acc = __builtin_amdgcn_mfma_f32_16x16x32_bf16(afr[2], w1f[nt][2], acc, 0, 0, 0);
                acc = __builtin_amdgcn_mfma_f32_16x16x32_bf16(afr[3], w1f[nt][3], acc, 0, 0, 0);
                float hv0 = acc[0] + t1v[nt]; hv0 = hv0 > 0.f ? hv0 : hv0*0.01f;
                float hv1 = acc[1] + t1v[nt]; hv1 = hv1 > 0.f ? hv1 : hv1*0.01f;
                float hv2 = acc[2] + t1v[nt]; hv2 = hv2 > 0.f ? hv2 : hv2*0.01f;
                float hv3 = acc[3] + t1v[nt]; hv3 = hv3 > 0.f ? hv3 : hv3*0.01f;
                // pair adjacent o-channels via xor-1 exchange -> 2 x ds_write_b32
                float ov0 = __shfl_xor(hv0, 1);
                float ov1 = __shfl_xor(hv1, 1);
                float ov2 = __shfl_xor(hv2, 1);
                float ov3 = __shfl_xor(hv3, 1);
                bool odd = (l15 & 1);
                float lo0 = odd ? ov2 : hv0,  hi0 = odd ? hv2 : ov0;
                float lo1 = odd ? ov3 : hv1,  hi1 = odd ? hv3 : ov1;
                unsigned w0 = pk_trunc(lo0, hi0);
                unsigned w1 = pk_trunc(lo1, hi1);
                int col = g*32 + nt*8 + (l15 >> 1);
                int row = h*32 + ms*16 + q*4 + (odd ? 2 : 0);
                sH1[row*68 + col]     = w0;
                sH1[(row+1)*68 + col] = w1;
            }
        }
        __syncthreads();

        // ===== layer 2 (+BN fold) + layer 3 dot =====
        #pragma unroll
        for (int s = 0; s < 2; ++s) {
            short8 hfr[4];
            #pragma unroll
            for (int kt = 0; kt < 4; ++kt)
                hfr[kt] = *(const short8*)&sH1[(h*32 + s*16 + l15)*68 + kt*16 + q*4];

            float part[4] = {0.f, 0.f, 0.f, 0.f};
            #pragma unroll
            for (int nt = 0; nt < 2; ++nt) {
                f32x4 acc = {0.f, 0.f, 0.f, 0.f};
                acc = __builtin_amdgcn_mfma_f32_16x16x32_bf16(hfr[0], w2f[nt][0], acc, 0, 0, 0);
                acc = __builtin_amdgcn_mfma_f32_16x16x32_bf16(hfr[1], w2f[nt][1], acc, 0, 0, 0);
                acc = __builtin_amdgcn_mfma_f32_16x16x32_bf16(hfr[2], w2f[nt][2], acc, 0, 0, 0);
                acc = __builtin_amdgcn_mfma_f32_16x16x32_bf16(hfr[3], w2f[nt][3], acc, 0, 0, 0);
                #pragma unroll
                for (int r = 0; r < 4; ++r) {
                    float hv = acc[r] + t2v[nt];
                    hv = hv > 0.f ? hv : hv*0.01f;
                    part[r] = fmaf(hv, w3v[nt], part[r]);
                }
            }
            #pragma unroll
            for (int r = 0; r < 4; ++r) {
                part[r] += __shfl_xor(part[r], 1);
                part[r] += __shfl_xor(part[r], 2);
                part[r] += __shfl_xor(part[r], 4);
                part[r] += __shfl_xor(part[r], 8);
            }
            if (l15 == 0) {
                #pragma unroll
                for (int r = 0; r < 4; ++r)
                    sPart[g][h*32 + s*16 + q*4 + r] = part[r];
            }
        }
        __syncthreads();

        // ===== epilogue: 64 pairs (2 full 128B lines) =====
        if (t < 64) {
            float logit = sPart[0][t] + sPart[1][t] + b3v;
            float sg = 1.f / (1.f + __expf(-logit));
            int i = i0 + ch*2 + (t >> 5);
            int j = j0 + (t & 31);
            float epl = (i == j) ? 0.f : ep[((size_t)(b*NPTS + i))*NPTS + j];
            ep_out[((size_t)(b*NPTS + i))*NPTS + j] = sg * epl;
        }
        // sH1 rewrites (next chunk) are fenced by the barrier pair; sPart
        // rewrites happen only after the next first barrier.
    }
}

// ---- kernel 2: per-row top-k mask + L1 renorm + diag + row norm ----
__device__ __forceinline__ float block_reduce_sum512(float v, float* red) {
    #pragma unroll
    for (int off = 32; off; off >>= 1) v += __shfl_down(v, off);
    int wid = threadIdx.x >> 6;
    if ((threadIdx.x & 63) == 0) red[wid] = v;
    __syncthreads();
    float s = ((red[0] + red[1]) + (red[2] + red[3]))
            + ((red[4] + red[5]) + (red[6] + red[7]));
    __syncthreads();
    return s;
}

__global__ __launch_bounds__(512)
void topk_norm_kernel(const float* __restrict__ ep_gen, float* __restrict__ ep_io) {
    __shared__ __align__(16) float r[NPTS];
    __shared__ float red[8];
    const int row = blockIdx.x;          // b*512 + i
    const int i   = row & (NPTS - 1);
    const int t   = threadIdx.x;
    const float* gen = &ep_gen[(size_t)row * NPTS];
    float* io        = &ep_io [(size_t)row * NPTS];

    float v = io[t];
    r[t] = v;
    float gv = (t == i) ? 0.f : gen[t];
    __syncthreads();

    float s_last = block_reduce_sum512(gv, red);

    // rank by strict-greater count; sigmoid*uniform values make exact float
    // ties measure-zero, so lax.top_k's index tiebreak can't change the set.
    int c = 0;
    #pragma unroll 4
    for (int k = 0; k < NPTS; k += 4) {
        float4 rv = *(const float4*)&r[k];   // wave-uniform LDS broadcast
        c += (rv.x > v) + (rv.y > v) + (rv.z > v) + (rv.w > v);
    }
    float m = (c < KVAL) ? v : 0.f;

    float l1 = block_reduce_sum512(m, red);
    float scale = s_last / fmaxf(l1, 1e-12f);
    float f = m*scale + ((t == i) ? 1.f : 0.f) + 1e-6f;

    float s2 = block_reduce_sum512(f, red);
    io[t] = f / s2;
}

extern "C" void kernel_launch(void* const* d_in, const int* in_sizes, int n_in,
                              void* d_out, int out_size, void* d_ws, size_t ws_size,
                              hipStream_t stream) {
    const float* vp  = (const float*)d_in[0];
    const float* ep  = (const float*)d_in[1];
    const float* W1  = (const float*)d_in[2];
    const float* g1  = (const float*)d_in[3];
    const float* be1 = (const float*)d_in[4];
    const float* m1  = (const float*)d_in[5];
    const float* v1  = (const float*)d_in[6];
    const float* W2  = (const float*)d_in[7];
    const float* g2  = (const float*)d_in[8];
    const float* be2 = (const float*)d_in[9];
    const float* m2  = (const float*)d_in[10];
    const float* v2  = (const float*)d_in[11];
    const float* W3  = (const float*)d_in[12];
    const float* b3  = (const float*)d_in[13];

    float* out    = (float*)d_out;
    float* ep_out = out;                          // [2,512,512]
    float* ns_out = out + (size_t)NB*NPTS*NPTS;   // [2,512,512]

    dim3 grid(NPTS/32, NPTS/16, NB);              // 1024 blocks, j-tiles 128B wide
    mlp_mfma_kernel<<<grid, dim3(256), 0, stream>>>(vp, ep, W1, g1, be1, m1, v1,
                                                    W2, g2, be2, m2, v2, W3, b3,
                                                    ep_out, ns_out);
    topk_norm_kernel<<<dim3(NB*NPTS), dim3(512), 0, stream>>>(ep, ep_out);
}

// Round 6
// 150.290 us; speedup vs baseline: 2.0893x; 1.2072x over previous
//
#include <hip/hip_runtime.h>
#include <math.h>

#define NPTS 512
#define CH   128
#define NB   2
#define KVAL 460   // int(512 * (1 - 0.1))

typedef __attribute__((ext_vector_type(8))) short short8;
typedef __attribute__((ext_vector_type(4))) float f32x4;

union S8U { short8 s8; unsigned u[4]; uint4 u4; };

__device__ __forceinline__ unsigned short f2bf_rne(float f) {
    unsigned int u = __float_as_uint(f);
    u += 0x7fffu + ((u >> 16) & 1u);
    return (unsigned short)(u >> 16);
}
__device__ __forceinline__ unsigned pk_rne(float a, float b) {
    return ((unsigned)f2bf_rne(a)) | (((unsigned)f2bf_rne(b)) << 16);
}
// pack by truncation: one v_perm_b32 (d^2 values feeding MFMA only)
__device__ __forceinline__ unsigned pk_trunc(float a, float b) {
    return __builtin_amdgcn_perm(__float_as_uint(b), __float_as_uint(a), 0x07060302u);
}

// ---- prep: BN-folded bf16 weight fragments, fragment-ordered in ws ----
// wsp[idx*64 + lane] = uint4 B-fragment piece for (o,k-block) of W1 (idx<2048)
// and W2 (2048+idx). Saves ~1100 VALU of packing per mlp block.
__global__ __launch_bounds__(256)
void prep_weights(const float* __restrict__ W1, const float* __restrict__ g1,
                  const float* __restrict__ v1,
                  const float* __restrict__ W2, const float* __restrict__ g2,
                  const float* __restrict__ v2, uint4* __restrict__ wsp)
{
    __shared__ float s1[CH], s2[64];
    int t = threadIdx.x;
    if (t < CH) s1[t] = g1[t] * rsqrtf(v1[t] + 1e-5f);
    if (t < 64) s2[t] = g2[t] * rsqrtf(v2[t] + 1e-5f);
    __syncthreads();
    for (int e = t; e < 2048; e += 256) {
        int idx = e >> 6, lane = e & 63;
        int g = idx >> 4, nt = (idx >> 2) & 3, kt = idx & 3;
        int o = g*64 + nt*16 + (lane & 15);
        int kb = kt*32 + (lane >> 4)*8;
        float s = s1[o];
        const float* p = &W1[(size_t)o*CH + kb];
        uint4 v;
        v.x = pk_rne(p[0]*s, p[1]*s);
        v.y = pk_rne(p[2]*s, p[3]*s);
        v.z = pk_rne(p[4]*s, p[5]*s);
        v.w = pk_rne(p[6]*s, p[7]*s);
        wsp[e] = v;
    }
    for (int e = t; e < 1024; e += 256) {
        int idx = e >> 6, lane = e & 63;
        int g = idx >> 3, nt = (idx >> 2) & 1, kt = idx & 3;
        int o = g*32 + nt*16 + (lane & 15);
        int kb = kt*32 + (lane >> 4)*8;
        float s = s2[o];
        const float* p = &W2[(size_t)o*CH + kb];
        uint4 v;
        v.x = pk_rne(p[0]*s, p[1]*s);
        v.y = pk_rne(p[2]*s, p[3]*s);
        v.z = pk_rne(p[4]*s, p[5]*s);
        v.w = pk_rne(p[6]*s, p[7]*s);
        wsp[2048 + e] = v;
    }
}

// Block = 8i x 32j sub-tile. TRI: only supertiles ti<=tj (53% of pair work,
// symmetry of d^2); mirrors done by mirror_kernel. 4 waves: h = wave&1 ->
// i-row in 2-row chunk, g = wave>>1 -> channel half.
// Constraints baked in: j-width 32 (full 128B store lines, R3); fp32 LDS vp
// (no unpack VALU, R2); launch_bounds cap >> natural VGPR use (R4 spill).
template<bool TRI>
__global__ __launch_bounds__(256, 3)
void mlp_mfma_kernel(const float* __restrict__ vp, const float* __restrict__ ep,
                     const uint4* __restrict__ wsp,
                     const float* __restrict__ W1,
                     const float* __restrict__ g1, const float* __restrict__ be1,
                     const float* __restrict__ m1, const float* __restrict__ v1,
                     const float* __restrict__ W2,
                     const float* __restrict__ g2, const float* __restrict__ be2,
                     const float* __restrict__ m2, const float* __restrict__ v2,
                     const float* __restrict__ W3, const float* __restrict__ b3,
                     float* __restrict__ ep_out, float* __restrict__ ns_out,
                     float* __restrict__ sg_out)
{
    __shared__ __align__(16) float    sVI[8*132];    //  4,224 B
    __shared__ __align__(16) float    sVJ[32*132];   // 16,896 B
    __shared__ __align__(16) unsigned sH1[64*68];    // 17,408 B (bf16x2)
    __shared__ float sPart[2][64];                   //    512 B

    const int t    = threadIdx.x;
    const int lane = t & 63;
    const int w    = t >> 6;
    const int h    = w & 1;
    const int g    = w >> 1;
    const int l15  = lane & 15;
    const int q    = lane >> 4;
    const int q8   = q * 8;
    const int b    = blockIdx.y;

    int i0, j0;
    if (TRI) {
        int x = blockIdx.x;          // [0,544)
        int sub = x & 3;
        int s = x >> 2;              // [0,136) upper-tri supertile
        int ti = 0;
        while (s >= 16 - ti) { s -= 16 - ti; ++ti; }
        i0 = ti*32 + sub*8;
        j0 = (ti + s)*32;
    } else {
        i0 = (blockIdx.x >> 4) * 8;
        j0 = (blockIdx.x & 15) * 32;
    }

    // ---- stage vp tiles in fp32 (coalesced float4, zero unpack later) ----
    {
        int r = t >> 5, c4 = (t & 31) * 4;
        *(float4*)&sVI[r*132 + c4] = *(const float4*)&vp[((size_t)(b*NPTS + i0 + r))*CH + c4];
    }
    for (int k = 0; k < 4; ++k) {
        int idx = k*256 + t;
        int r = idx >> 5, c4 = (idx & 31) * 4;
        *(float4*)&sVJ[r*132 + c4] = *(const float4*)&vp[((size_t)(b*NPTS + j0 + r))*CH + c4];
    }

    // ---- weight fragments ----
    short8 w1f[4][4]; float t1v[4];
    short8 w2f[2][4]; float t2v[2], w3v[2];
    if (TRI) {
        #pragma unroll
        for (int nt = 0; nt < 4; ++nt)
            #pragma unroll
            for (int kt = 0; kt < 4; ++kt) {
                S8U u; u.u4 = wsp[((g*4 + nt)*4 + kt)*64 + lane];
                w1f[nt][kt] = u.s8;
            }
        #pragma unroll
        for (int nt = 0; nt < 2; ++nt)
            #pragma unroll
            for (int kt = 0; kt < 4; ++kt) {
                S8U u; u.u4 = wsp[2048 + ((g*2 + nt)*4 + kt)*64 + lane];
                w2f[nt][kt] = u.s8;
            }
    } else {
        #pragma unroll
        for (int nt = 0; nt < 4; ++nt) {
            int o = g*64 + nt*16 + l15;
            float s = g1[o] * rsqrtf(v1[o] + 1e-5f);
            #pragma unroll
            for (int kt = 0; kt < 4; ++kt) {
                const float* p = &W1[(size_t)o*CH + kt*32 + q8];
                float4 x0 = *(const float4*)p;
                float4 x1 = *(const float4*)(p + 4);
                S8U u;
                u.u[0] = pk_rne(x0.x*s, x0.y*s);
                u.u[1] = pk_rne(x0.z*s, x0.w*s);
                u.u[2] = pk_rne(x1.x*s, x1.y*s);
                u.u[3] = pk_rne(x1.z*s, x1.w*s);
                w1f[nt][kt] = u.s8;
            }
        }
        #pragma unroll
        for (int nt = 0; nt < 2; ++nt) {
            int o = g*32 + nt*16 + l15;
            float s = g2[o] * rsqrtf(v2[o] + 1e-5f);
            #pragma unroll
            for (int kt = 0; kt < 4; ++kt) {
                const float* p = &W2[(size_t)o*CH + kt*32 + q8];
                float4 x0 = *(const float4*)p;
                float4 x1 = *(const float4*)(p + 4);
                S8U u;
                u.u[0] = pk_rne(x0.x*s, x0.y*s);
                u.u[1] = pk_rne(x0.z*s, x0.w*s);
                u.u[2] = pk_rne(x1.x*s, x1.y*s);
                u.u[3] = pk_rne(x1.z*s, x1.w*s);
                w2f[nt][kt] = u.s8;
            }
        }
    }
    #pragma unroll
    for (int nt = 0; nt < 4; ++nt) {
        int o = g*64 + nt*16 + l15;
        float s = g1[o] * rsqrtf(v1[o] + 1e-5f);
        t1v[nt] = be1[o] - m1[o]*s;
    }
    #pragma unroll
    for (int nt = 0; nt < 2; ++nt) {
        int o = g*32 + nt*16 + l15;
        float s = g2[o] * rsqrtf(v2[o] + 1e-5f);
        t2v[nt] = be2[o] - m2[o]*s;
        w3v[nt] = W3[o];
    }
    const float b3v = b3[0];
    __syncthreads();

    // ---- 4 chunks of 2 i-rows x 32 j = 64 pairs ----
    #pragma unroll 1
    for (int ch = 0; ch < 4; ++ch) {
        const int iirow = ch*2 + h;

        // ===== layer 1: fp32 A-build in MFMA layout; ns free in fp32 =====
        #pragma unroll
        for (int ms = 0; ms < 2; ++ms) {
            short8 afr[4];
            float ns = 0.f;
            #pragma unroll
            for (int kt = 0; kt < 4; ++kt) {
                const float* vi = &sVI[iirow*132 + kt*32 + q8];           // broadcast
                const float* vj = &sVJ[(ms*16 + l15)*132 + kt*32 + q8];   // per-lane
                float4 a0 = *(const float4*)vi, a1 = *(const float4*)(vi + 4);
                float4 c0 = *(const float4*)vj, c1 = *(const float4*)(vj + 4);
                float d0 = a0.x - c0.x, d1 = a0.y - c0.y, d2 = a0.z - c0.z, d3 = a0.w - c0.w;
                float d4 = a1.x - c1.x, d5 = a1.y - c1.y, d6 = a1.z - c1.z, d7 = a1.w - c1.w;
                float p0 = d0*d0, p1 = d1*d1, p2 = d2*d2, p3 = d3*d3;
                float p4 = d4*d4, p5 = d5*d5, p6 = d6*d6, p7 = d7*d7;
                ns += ((p0 + p1) + (p2 + p3)) + ((p4 + p5) + (p6 + p7));
                S8U u;
                u.u[0] = pk_trunc(p0, p1);
                u.u[1] = pk_trunc(p2, p3);
                u.u[2] = pk_trunc(p4, p5);
                u.u[3] = pk_trunc(p6, p7);
                afr[kt] = u.s8;
            }
            ns += __shfl_xor(ns, 16);
            ns += __shfl_xor(ns, 32);
            if (g == 0 && lane < 16) {
                ns_out[((size_t)(b*NPTS + i0 + iirow))*NPTS + j0 + ms*16 + lane] = -ns;
            }

            #pragma unroll
            for (int nt = 0; nt < 4; ++nt) {
                f32x4 acc = {0.f, 0.f, 0.f, 0.f};
                acc = __builtin_amdgcn_mfma_f32_16x16x32_bf16(afr[0], w1f[nt][0], acc, 0, 0, 0);
                acc = __builtin_amdgcn_mfma_f32_16x16x32_bf16(afr[1], w1f[nt][1], acc, 0, 0, 0);
                acc = __builtin_amdgcn_mfma_f32_16x16x32_bf16(afr[2], w1f[nt][2], acc, 0, 0, 0);
                acc = __builtin_amdgcn_mfma_f32_16x16x32_bf16(afr[3], w1f[nt][3], acc, 0, 0, 0);
                float hv0 = acc[0] + t1v[nt]; hv0 = hv0 > 0.f ? hv0 : hv0*0.01f;
                float hv1 = acc[1] + t1v[nt]; hv1 = hv1 > 0.f ? hv1 : hv1*0.01f;
                float hv2 = acc[2] + t1v[nt]; hv2 = hv2 > 0.f ? hv2 : hv2*0.01f;
                float hv3 = acc[3] + t1v[nt]; hv3 = hv3 > 0.f ? hv3 : hv3*0.01f;
                // pair adjacent o-channels via xor-1 -> 2 x ds_write_b32
                float ov0 = __shfl_xor(hv0, 1);
                float ov1 = __shfl_xor(hv1, 1);
                float ov2 = __shfl_xor(hv2, 1);
                float ov3 = __shfl_xor(hv3, 1);
                bool odd = (l15 & 1);
                float lo0 = odd ? ov2 : hv0,  hi0 = odd ? hv2 : ov0;
                float lo1 = odd ? ov3 : hv1,  hi1 = odd ? hv3 : ov1;
                unsigned w0 = pk_trunc(lo0, hi0);
                unsigned w1 = pk_trunc(lo1, hi1);
                int col = g*32 + nt*8 + (l15 >> 1);
                int row = h*32 + ms*16 + q*4 + (odd ? 2 : 0);
                sH1[row*68 + col]     = w0;
                sH1[(row+1)*68 + col] = w1;
            }
        }
        __syncthreads();

        // ===== layer 2 (+BN fold) + layer 3 dot =====
        #pragma unroll
        for (int s = 0; s < 2; ++s) {
            short8 hfr[4];
            #pragma unroll
            for (int kt = 0; kt < 4; ++kt)
                hfr[kt] = *(const short8*)&sH1[(h*32 + s*16 + l15)*68 + kt*16 + q*4];

            float part[4] = {0.f, 0.f, 0.f, 0.f};
            #pragma unroll
            for (int nt = 0; nt < 2; ++nt) {
                f32x4 acc = {0.f, 0.f, 0.f, 0.f};
                acc = __builtin_amdgcn_mfma_f32_16x16x32_bf16(hfr[0], w2f[nt][0], acc, 0, 0, 0);
                acc = __builtin_amdgcn_mfma_f32_16x16x32_bf16(hfr[1], w2f[nt][1], acc, 0, 0, 0);
                acc = __builtin_amdgcn_mfma_f32_16x16x32_bf16(hfr[2], w2f[nt][2], acc, 0, 0, 0);
                acc = __builtin_amdgcn_mfma_f32_16x16x32_bf16(hfr[3], w2f[nt][3], acc, 0, 0, 0);
                #pragma unroll
                for (int r = 0; r < 4; ++r) {
                    float hv = acc[r] + t2v[nt];
                    hv = hv > 0.f ? hv : hv*0.01f;
                    part[r] = fmaf(hv, w3v[nt], part[r]);
                }
            }
            #pragma unroll
            for (int r = 0; r < 4; ++r) {
                part[r] += __shfl_xor(part[r], 1);
                part[r] += __shfl_xor(part[r], 2);
                part[r] += __shfl_xor(part[r], 4);
                part[r] += __shfl_xor(part[r], 8);
            }
            if (l15 == 0) {
                #pragma unroll
                for (int r = 0; r < 4; ++r)
                    sPart[g][h*32 + s*16 + q*4 + r] = part[r];
            }
        }
        __syncthreads();

        // ===== epilogue: 64 pairs (2 full 128B lines) =====
        if (t < 64) {
            float logit = sPart[0][t] + sPart[1][t] + b3v;
            float sg = 1.f / (1.f + __expf(-logit));
            int i = i0 + ch*2 + (t >> 5);
            int j = j0 + (t & 31);
            if (TRI) sg_out[((size_t)(b*NPTS + i))*NPTS + j] = sg;
            float epl = (i == j) ? 0.f : ep[((size_t)(b*NPTS + i))*NPTS + j];
            ep_out[((size_t)(b*NPTS + i))*NPTS + j] = sg * epl;
        }
    }
}

// ---- mirror: lower-triangle supertiles from upper, LDS transpose ----
// All global reads/writes are full 128B lines.
__global__ __launch_bounds__(256)
void mirror_kernel(const float* __restrict__ ep, const float* __restrict__ sg_buf,
                   float* __restrict__ ep_out, float* __restrict__ ns_out)
{
    __shared__ float sgS[32*33], nsS[32*33];
    const int b = blockIdx.y;
    int m = blockIdx.x;               // [0,120) strictly-lower supertiles
    int ti = 1;
    while (m >= ti) { m -= ti; ++ti; }
    const int I0 = ti*32, J0 = m*32;  // target (lower); source = (J0 rows, I0 cols)
    const int t = threadIdx.x;

    for (int k = 0; k < 4; ++k) {
        int idx = k*256 + t;
        int r = idx >> 5, c = idx & 31;
        sgS[r*33 + c] = sg_buf[((size_t)(b*NPTS + J0 + r))*NPTS + I0 + c];
        nsS[r*33 + c] = ns_out[((size_t)(b*NPTS + J0 + r))*NPTS + I0 + c];
    }
    __syncthreads();
    for (int k = 0; k < 4; ++k) {
        int idx = k*256 + t;
        int rr = idx >> 5, cc = idx & 31;
        size_t off = ((size_t)(b*NPTS + I0 + rr))*NPTS + J0 + cc;
        float sg = sgS[cc*33 + rr];       // transposed read, conflict-free (33)
        ep_out[off] = sg * ep[off];       // I!=J always (ti>tj)
        ns_out[off] = nsS[cc*33 + rr];
    }
}

// ---- topk + L1 renorm + diag + row norm ----
__device__ __forceinline__ float block_reduce_sum512(float v, float* red) {
    #pragma unroll
    for (int off = 32; off; off >>= 1) v += __shfl_down(v, off);
    int wid = threadIdx.x >> 6;
    if ((threadIdx.x & 63) == 0) red[wid] = v;
    __syncthreads();
    float s = ((red[0] + red[1]) + (red[2] + red[3]))
            + ((red[4] + red[5]) + (red[6] + red[7]));
    __syncthreads();
    return s;
}

__global__ __launch_bounds__(512)
void topk_norm_kernel(const float* __restrict__ ep_gen, float* __restrict__ ep_io) {
    __shared__ __align__(16) float r[NPTS];
    __shared__ float red[8];
    const int row = blockIdx.x;          // b*512 + i
    const int i   = row & (NPTS - 1);
    const int t   = threadIdx.x;
    const float* gen = &ep_gen[(size_t)row * NPTS];
    float* io        = &ep_io [(size_t)row * NPTS];

    float v = io[t];
    r[t] = v;
    float gv = (t == i) ? 0.f : gen[t];
    __syncthreads();

    float s_last = block_reduce_sum512(gv, red);

    // rank by strict-greater count; sigmoid*uniform values make exact float
    // ties measure-zero, so lax.top_k's index tiebreak can't change the set.
    int c = 0;
    #pragma unroll 4
    for (int k = 0; k < NPTS; k += 4) {
        float4 rv = *(const float4*)&r[k];
        c += (rv.x > v) + (rv.y > v) + (rv.z > v) + (rv.w > v);
    }
    float m = (c < KVAL) ? v : 0.f;

    float l1 = block_reduce_sum512(m, red);
    float scale = s_last / fmaxf(l1, 1e-12f);
    float f = m*scale + ((t == i) ? 1.f : 0.f) + 1e-6f;

    float s2 = block_reduce_sum512(f, red);
    io[t] = f / s2;
}

extern "C" void kernel_launch(void* const* d_in, const int* in_sizes, int n_in,
                              void* d_out, int out_size, void* d_ws, size_t ws_size,
                              hipStream_t stream) {
    const float* vp  = (const float*)d_in[0];
    const float* ep  = (const float*)d_in[1];
    const float* W1  = (const float*)d_in[2];
    const float* g1  = (const float*)d_in[3];
    const float* be1 = (const float*)d_in[4];
    const float* m1  = (const float*)d_in[5];
    const float* v1  = (const float*)d_in[6];
    const float* W2  = (const float*)d_in[7];
    const float* g2  = (const float*)d_in[8];
    const float* be2 = (const float*)d_in[9];
    const float* m2  = (const float*)d_in[10];
    const float* v2  = (const float*)d_in[11];
    const float* W3  = (const float*)d_in[12];
    const float* b3  = (const float*)d_in[13];

    float* out    = (float*)d_out;
    float* ep_out = out;                          // [2,512,512]
    float* ns_out = out + (size_t)NB*NPTS*NPTS;   // [2,512,512]

    const size_t need = 49152 + (size_t)NB*NPTS*NPTS*sizeof(float);  // 48K + 2M
    if (ws_size >= need) {
        uint4* wsp    = (uint4*)d_ws;
        float* sg_buf = (float*)((char*)d_ws + 49152);
        prep_weights<<<dim3(1), dim3(256), 0, stream>>>(W1, g1, v1, W2, g2, v2, wsp);
        mlp_mfma_kernel<true><<<dim3(544, NB), dim3(256), 0, stream>>>(
            vp, ep, wsp, W1, g1, be1, m1, v1, W2, g2, be2, m2, v2, W3, b3,
            ep_out, ns_out, sg_buf);
        mirror_kernel<<<dim3(120, NB), dim3(256), 0, stream>>>(ep, sg_buf, ep_out, ns_out);
    } else {
        mlp_mfma_kernel<false><<<dim3(1024, NB), dim3(256), 0, stream>>>(
            vp, ep, nullptr, W1, g1, be1, m1, v1, W2, g2, be2, m2, v2, W3, b3,
            ep_out, ns_out, nullptr);
    }
    topk_norm_kernel<<<dim3(NB*NPTS), dim3(512), 0, stream>>>(ep, ep_out);
}

// Round 7
// 147.081 us; speedup vs baseline: 2.1349x; 1.0218x over previous
//
#include <hip/hip_runtime.h>
#include <math.h>

#define NPTS 512
#define CH   128
#define NB   2
#define KVAL 460   // int(512 * (1 - 0.1))

typedef __attribute__((ext_vector_type(8))) short short8;
typedef __attribute__((ext_vector_type(4))) float f32x4;

union S8U { short8 s8; unsigned u[4]; uint4 u4; };

__device__ __forceinline__ unsigned short f2bf_rne(float f) {
    unsigned int u = __float_as_uint(f);
    u += 0x7fffu + ((u >> 16) & 1u);
    return (unsigned short)(u >> 16);
}
__device__ __forceinline__ unsigned pk_rne(float a, float b) {
    return ((unsigned)f2bf_rne(a)) | (((unsigned)f2bf_rne(b)) << 16);
}
// pack by truncation: one v_perm_b32 (d^2 values feeding MFMA only)
__device__ __forceinline__ unsigned pk_trunc(float a, float b) {
    return __builtin_amdgcn_perm(__float_as_uint(b), __float_as_uint(a), 0x07060302u);
}

// ---- prep: BN-folded bf16 weight B-fragments, fragment-ordered in ws ----
// wsp[idx*64+lane]: W1 idx in [0,2048) (idx = (g*16+nt*4+kt)*64...), W2 at 2048+.
__global__ __launch_bounds__(256)
void prep_weights(const float* __restrict__ W1, const float* __restrict__ g1,
                  const float* __restrict__ v1,
                  const float* __restrict__ W2, const float* __restrict__ g2,
                  const float* __restrict__ v2, uint4* __restrict__ wsp)
{
    int e = blockIdx.x * 256 + threadIdx.x;   // [0, 3072)
    if (e < 2048) {
        int idx = e >> 6, lane = e & 63;
        int g = idx >> 4, nt = (idx >> 2) & 3, kt = idx & 3;
        int o = g*64 + nt*16 + (lane & 15);
        int kb = kt*32 + (lane >> 4)*8;
        float s = g1[o] * rsqrtf(v1[o] + 1e-5f);
        const float* p = &W1[(size_t)o*CH + kb];
        uint4 v;
        v.x = pk_rne(p[0]*s, p[1]*s);
        v.y = pk_rne(p[2]*s, p[3]*s);
        v.z = pk_rne(p[4]*s, p[5]*s);
        v.w = pk_rne(p[6]*s, p[7]*s);
        wsp[e] = v;
    } else if (e < 3072) {
        int e2 = e - 2048;
        int idx = e2 >> 6, lane = e2 & 63;
        int g = idx >> 3, nt = (idx >> 2) & 1, kt = idx & 3;
        int o = g*32 + nt*16 + (lane & 15);
        int kb = kt*32 + (lane >> 4)*8;
        float s = g2[o] * rsqrtf(v2[o] + 1e-5f);
        const float* p = &W2[(size_t)o*CH + kb];
        uint4 v;
        v.x = pk_rne(p[0]*s, p[1]*s);
        v.y = pk_rne(p[2]*s, p[3]*s);
        v.z = pk_rne(p[4]*s, p[5]*s);
        v.w = pk_rne(p[6]*s, p[7]*s);
        wsp[e] = v;
    }
}

// TRI mlp: block = 16i x 32j sub-tile of an upper supertile (ti<=tj).
// Register-budget design (R6 lesson: 96 AGPR weight frags + 84 arch = ~180
// total -> 2 waves/SIMD cap): w1f loaded once from prep-packed wsp (64 regs),
// w2f streamed per-chunk (transient), total ~148 -> 3 waves/SIMD.
// j-width 32 = full 128B store lines (R3 lesson). fp32 LDS vp (R2/R5 lesson).
__global__ __launch_bounds__(256, 3)
void mlp_tri_kernel(const float* __restrict__ vp, const uint4* __restrict__ wsp,
                    const float* __restrict__ g1, const float* __restrict__ be1,
                    const float* __restrict__ m1, const float* __restrict__ v1,
                    const float* __restrict__ g2, const float* __restrict__ be2,
                    const float* __restrict__ m2, const float* __restrict__ v2,
                    const float* __restrict__ W3, const float* __restrict__ b3,
                    float* __restrict__ ns_out, float* __restrict__ sg_out)
{
    __shared__ __align__(16) float    sVI[16*132];   //  8,448 B
    __shared__ __align__(16) float    sVJ[32*132];   // 16,896 B
    __shared__ __align__(16) unsigned sH1[64*68];    // 17,408 B (bf16x2)
    __shared__ float sPart[2][64];                   //    512 B  -> 43.3 KB

    const int t    = threadIdx.x;
    const int lane = t & 63;
    const int w    = t >> 6;
    const int h    = w & 1;
    const int g    = w >> 1;
    const int l15  = lane & 15;
    const int q    = lane >> 4;
    const int q8   = q * 8;
    const int b    = blockIdx.y;

    int x = blockIdx.x;              // [0, 272)
    int sub = x & 1;
    int s = x >> 1;                  // [0,136) upper-tri supertile
    int ti = 0;
    while (s >= 16 - ti) { s -= 16 - ti; ++ti; }
    const int i0 = ti*32 + sub*16;
    const int j0 = (ti + s)*32;

    // ---- stage vp tiles in fp32 (coalesced float4) ----
    for (int k = 0; k < 2; ++k) {
        int idx = k*256 + t;
        int r = idx >> 5, c4 = (idx & 31) * 4;
        *(float4*)&sVI[r*132 + c4] = *(const float4*)&vp[((size_t)(b*NPTS + i0 + r))*CH + c4];
    }
    for (int k = 0; k < 4; ++k) {
        int idx = k*256 + t;
        int r = idx >> 5, c4 = (idx & 31) * 4;
        *(float4*)&sVJ[r*132 + c4] = *(const float4*)&vp[((size_t)(b*NPTS + j0 + r))*CH + c4];
    }

    // ---- w1f: one-time coalesced load of prep-packed fragments ----
    short8 w1f[4][4];
    #pragma unroll
    for (int nt = 0; nt < 4; ++nt)
        #pragma unroll
        for (int kt = 0; kt < 4; ++kt) {
            S8U u; u.u4 = wsp[((g*4 + nt)*4 + kt)*64 + lane];
            w1f[nt][kt] = u.s8;
        }

    // ---- BN shifts / W3 (per-lane) ----
    float t1v[4], t2v[2], w3v[2];
    #pragma unroll
    for (int nt = 0; nt < 4; ++nt) {
        int o = g*64 + nt*16 + l15;
        float sc = g1[o] * rsqrtf(v1[o] + 1e-5f);
        t1v[nt] = be1[o] - m1[o]*sc;
    }
    #pragma unroll
    for (int nt = 0; nt < 2; ++nt) {
        int o = g*32 + nt*16 + l15;
        float sc = g2[o] * rsqrtf(v2[o] + 1e-5f);
        t2v[nt] = be2[o] - m2[o]*sc;
        w3v[nt] = W3[o];
    }
    const float b3v = b3[0];
    __syncthreads();

    // ---- 8 chunks of 2 i-rows x 32 j = 64 pairs ----
    #pragma unroll 1
    for (int ch = 0; ch < 8; ++ch) {
        const int iirow = ch*2 + h;

        // ===== layer 1: fp32 A-build in MFMA layout; ns free in fp32 =====
        #pragma unroll
        for (int ms = 0; ms < 2; ++ms) {
            short8 afr[4];
            float ns = 0.f;
            #pragma unroll
            for (int kt = 0; kt < 4; ++kt) {
                const float* vi = &sVI[iirow*132 + kt*32 + q8];           // broadcast
                const float* vj = &sVJ[(ms*16 + l15)*132 + kt*32 + q8];   // per-lane
                float4 a0 = *(const float4*)vi, a1 = *(const float4*)(vi + 4);
                float4 c0 = *(const float4*)vj, c1 = *(const float4*)(vj + 4);
                float d0 = a0.x - c0.x, d1 = a0.y - c0.y, d2 = a0.z - c0.z, d3 = a0.w - c0.w;
                float d4 = a1.x - c1.x, d5 = a1.y - c1.y, d6 = a1.z - c1.z, d7 = a1.w - c1.w;
                float p0 = d0*d0, p1 = d1*d1, p2 = d2*d2, p3 = d3*d3;
                float p4 = d4*d4, p5 = d5*d5, p6 = d6*d6, p7 = d7*d7;
                ns += ((p0 + p1) + (p2 + p3)) + ((p4 + p5) + (p6 + p7));
                S8U u;
                u.u[0] = pk_trunc(p0, p1);
                u.u[1] = pk_trunc(p2, p3);
                u.u[2] = pk_trunc(p4, p5);
                u.u[3] = pk_trunc(p6, p7);
                afr[kt] = u.s8;
            }
            ns += __shfl_xor(ns, 16);
            ns += __shfl_xor(ns, 32);
            if (g == 0 && lane < 16) {
                ns_out[((size_t)(b*NPTS + i0 + iirow))*NPTS + j0 + ms*16 + lane] = -ns;
            }

            #pragma unroll
            for (int nt = 0; nt < 4; ++nt) {
                f32x4 acc = {0.f, 0.f, 0.f, 0.f};
                acc = __builtin_amdgcn_mfma_f32_16x16x32_bf16(afr[0], w1f[nt][0], acc, 0, 0, 0);
                acc = __builtin_amdgcn_mfma_f32_16x16x32_bf16(afr[1], w1f[nt][1], acc, 0, 0, 0);
                acc = __builtin_amdgcn_mfma_f32_16x16x32_bf16(afr[2], w1f[nt][2], acc, 0, 0, 0);
                acc = __builtin_amdgcn_mfma_f32_16x16x32_bf16(afr[3], w1f[nt][3], acc, 0, 0, 0);
                float hv0 = acc[0] + t1v[nt]; hv0 = hv0 > 0.f ? hv0 : hv0*0.01f;
                float hv1 = acc[1] + t1v[nt]; hv1 = hv1 > 0.f ? hv1 : hv1*0.01f;
                float hv2 = acc[2] + t1v[nt]; hv2 = hv2 > 0.f ? hv2 : hv2*0.01f;
                float hv3 = acc[3] + t1v[nt]; hv3 = hv3 > 0.f ? hv3 : hv3*0.01f;
                float ov0 = __shfl_xor(hv0, 1);
                float ov1 = __shfl_xor(hv1, 1);
                float ov2 = __shfl_xor(hv2, 1);
                float ov3 = __shfl_xor(hv3, 1);
                bool odd = (l15 & 1);
                float lo0 = odd ? ov2 : hv0,  hi0 = odd ? hv2 : ov0;
                float lo1 = odd ? ov3 : hv1,  hi1 = odd ? hv3 : ov1;
                unsigned w0 = pk_trunc(lo0, hi0);
                unsigned w1 = pk_trunc(lo1, hi1);
                int col = g*32 + nt*8 + (l15 >> 1);
                int row = h*32 + ms*16 + q*4 + (odd ? 2 : 0);
                sH1[row*68 + col]     = w0;
                sH1[(row+1)*68 + col] = w1;
            }
        }
        // stream W2 frags for this chunk (transient; independent of sH1,
        // latency hidden by the barrier wait)
        S8U wf[8];
        #pragma unroll
        for (int e = 0; e < 8; ++e)
            wf[e].u4 = wsp[2048 + (g*8 + e)*64 + lane];
        __syncthreads();

        // ===== layer 2 (+BN fold) + layer 3 dot =====
        #pragma unroll
        for (int sidx = 0; sidx < 2; ++sidx) {
            short8 hfr[4];
            #pragma unroll
            for (int kt = 0; kt < 4; ++kt)
                hfr[kt] = *(const short8*)&sH1[(h*32 + sidx*16 + l15)*68 + kt*16 + q*4];

            float part[4] = {0.f, 0.f, 0.f, 0.f};
            #pragma unroll
            for (int nt = 0; nt < 2; ++nt) {
                f32x4 acc = {0.f, 0.f, 0.f, 0.f};
                acc = __builtin_amdgcn_mfma_f32_16x16x32_bf16(hfr[0], wf[nt*4+0].s8, acc, 0, 0, 0);
                acc = __builtin_amdgcn_mfma_f32_16x16x32_bf16(hfr[1], wf[nt*4+1].s8, acc, 0, 0, 0);
                acc = __builtin_amdgcn_mfma_f32_16x16x32_bf16(hfr[2], wf[nt*4+2].s8, acc, 0, 0, 0);
                acc = __builtin_amdgcn_mfma_f32_16x16x32_bf16(hfr[3], wf[nt*4+3].s8, acc, 0, 0, 0);
                #pragma unroll
                for (int r = 0; r < 4; ++r) {
                    float hv = acc[r] + t2v[nt];
                    hv = hv > 0.f ? hv : hv*0.01f;
                    part[r] = fmaf(hv, w3v[nt], part[r]);
                }
            }
            #pragma unroll
            for (int r = 0; r < 4; ++r) {
                part[r] += __shfl_xor(part[r], 1);
                part[r] += __shfl_xor(part[r], 2);
                part[r] += __shfl_xor(part[r], 4);
                part[r] += __shfl_xor(part[r], 8);
            }
            if (l15 == 0) {
                #pragma unroll
                for (int r = 0; r < 4; ++r)
                    sPart[g][h*32 + sidx*16 + q*4 + r] = part[r];
            }
        }
        __syncthreads();

        // ===== epilogue: raw sigmoid only (finish kernel applies ep_last) =====
        if (t < 64) {
            float logit = sPart[0][t] + sPart[1][t] + b3v;
            float sg = 1.f / (1.f + __expf(-logit));
            int i = i0 + ch*2 + (t >> 5);
            int j = j0 + (t & 31);
            sg_out[((size_t)(b*NPTS + i))*NPTS + j] = sg;   // full 128B lines
        }
    }
}

// ---- fallback (no ws): full-grid, in-kernel packing, direct ep_out ----
__global__ __launch_bounds__(256, 3)
void mlp_full_kernel(const float* __restrict__ vp, const float* __restrict__ ep,
                     const float* __restrict__ W1,
                     const float* __restrict__ g1, const float* __restrict__ be1,
                     const float* __restrict__ m1, const float* __restrict__ v1,
                     const float* __restrict__ W2,
                     const float* __restrict__ g2, const float* __restrict__ be2,
                     const float* __restrict__ m2, const float* __restrict__ v2,
                     const float* __restrict__ W3, const float* __restrict__ b3,
                     float* __restrict__ ep_out, float* __restrict__ ns_out)
{
    __shared__ __align__(16) float    sVI[8*132];
    __shared__ __align__(16) float    sVJ[32*132];
    __shared__ __align__(16) unsigned sH1[64*68];
    __shared__ float sPart[2][64];

    const int t    = threadIdx.x;
    const int lane = t & 63;
    const int w    = t >> 6;
    const int h    = w & 1;
    const int g    = w >> 1;
    const int l15  = lane & 15;
    const int q    = lane >> 4;
    const int q8   = q * 8;
    const int b    = blockIdx.y;
    const int i0   = (blockIdx.x >> 4) * 8;
    const int j0   = (blockIdx.x & 15) * 32;

    {
        int r = t >> 5, c4 = (t & 31) * 4;
        *(float4*)&sVI[r*132 + c4] = *(const float4*)&vp[((size_t)(b*NPTS + i0 + r))*CH + c4];
    }
    for (int k = 0; k < 4; ++k) {
        int idx = k*256 + t;
        int r = idx >> 5, c4 = (idx & 31) * 4;
        *(float4*)&sVJ[r*132 + c4] = *(const float4*)&vp[((size_t)(b*NPTS + j0 + r))*CH + c4];
    }
    short8 w1f[4][4]; float t1v[4];
    short8 w2f[2][4]; float t2v[2], w3v[2];
    #pragma unroll
    for (int nt = 0; nt < 4; ++nt) {
        int o = g*64 + nt*16 + l15;
        float sc = g1[o] * rsqrtf(v1[o] + 1e-5f);
        t1v[nt] = be1[o] - m1[o]*sc;
        #pragma unroll
        for (int kt = 0; kt < 4; ++kt) {
            const float* p = &W1[(size_t)o*CH + kt*32 + q8];
            float4 x0 = *(const float4*)p;
            float4 x1 = *(const float4*)(p + 4);
            S8U u;
            u.u[0] = pk_rne(x0.x*sc, x0.y*sc);
            u.u[1] = pk_rne(x0.z*sc, x0.w*sc);
            u.u[2] = pk_rne(x1.x*sc, x1.y*sc);
            u.u[3] = pk_rne(x1.z*sc, x1.w*sc);
            w1f[nt][kt] = u.s8;
        }
    }
    #pragma unroll
    for (int nt = 0; nt < 2; ++nt) {
        int o = g*32 + nt*16 + l15;
        float sc = g2[o] * rsqrtf(v2[o] + 1e-5f);
        t2v[nt] = be2[o] - m2[o]*sc;
        w3v[nt] = W3[o];
        #pragma unroll
        for (int kt = 0; kt < 4; ++kt) {
            const float* p = &W2[(size_t)o*CH + kt*32 + q8];
            float4 x0 = *(const float4*)p;
            float4 x1 = *(const float4*)(p + 4);
            S8U u;
            u.u[0] = pk_rne(x0.x*sc, x0.y*sc);
            u.u[1] = pk_rne(x0.z*sc, x0.w*sc);
            u.u[2] = pk_rne(x1.x*sc, x1.y*sc);
            u.u[3] = pk_rne(x1.z*sc, x1.w*sc);
            w2f[nt][kt] = u.s8;
        }
    }
    const float b3v = b3[0];
    __syncthreads();

    #pragma unroll 1
    for (int ch = 0; ch < 4; ++ch) {
        const int iirow = ch*2 + h;
        #pragma unroll
        for (int ms = 0; ms < 2; ++ms) {
            short8 afr[4];
            float ns = 0.f;
            #pragma unroll
            for (int kt = 0; kt < 4; ++kt) {
                const float* vi = &sVI[iirow*132 + kt*32 + q8];
                const float* vj = &sVJ[(ms*16 + l15)*132 + kt*32 + q8];
                float4 a0 = *(const float4*)vi, a1 = *(const float4*)(vi + 4);
                float4 c0 = *(const float4*)vj, c1 = *(const float4*)(vj + 4);
                float d0 = a0.x - c0.x, d1 = a0.y - c0.y, d2 = a0.z - c0.z, d3 = a0.w - c0.w;
                float d4 = a1.x - c1.x, d5 = a1.y - c1.y, d6 = a1.z - c1.z, d7 = a1.w - c1.w;
                float p0 = d0*d0, p1 = d1*d1, p2 = d2*d2, p3 = d3*d3;
                float p4 = d4*d4, p5 = d5*d5, p6 = d6*d6, p7 = d7*d7;
                ns += ((p0 + p1) + (p2 + p3)) + ((p4 + p5) + (p6 + p7));
                S8U u;
                u.u[0] = pk_trunc(p0, p1);
                u.u[1] = pk_trunc(p2, p3);
                u.u[2] = pk_trunc(p4, p5);
                u.u[3] = pk_trunc(p6, p7);
                afr[kt] = u.s8;
            }
            ns += __shfl_xor(ns, 16);
            ns += __shfl_xor(ns, 32);
            if (g == 0 && lane < 16)
                ns_out[((size_t)(b*NPTS + i0 + iirow))*NPTS + j0 + ms*16 + lane] = -ns;
            #pragma unroll
            for (int nt = 0; nt < 4; ++nt) {
                f32x4 acc = {0.f, 0.f, 0.f, 0.f};
                acc = __builtin_amdgcn_mfma_f32_16x16x32_bf16(afr[0], w1f[nt][0], acc, 0, 0, 0);
                acc = __builtin_amdgcn_mfma_f32_16x16x32_bf16(afr[1], w1f[nt][1], acc, 0, 0, 0);
                acc = __builtin_amdgcn_mfma_f32_16x16x32_bf16(afr[2], w1f[nt][2], acc, 0, 0, 0);
                acc = __builtin_amdgcn_mfma_f32_16x16x32_bf16(afr[3], w1f[nt][3], acc, 0, 0, 0);
                float hv0 = acc[0] + t1v[nt]; hv0 = hv0 > 0.f ? hv0 : hv0*0.01f;
                float hv1 = acc[1] + t1v[nt]; hv1 = hv1 > 0.f ? hv1 : hv1*0.01f;
                float hv2 = acc[2] + t1v[nt]; hv2 = hv2 > 0.f ? hv2 : hv2*0.01f;
                float hv3 = acc[3] + t1v[nt]; hv3 = hv3 > 0.f ? hv3 : hv3*0.01f;
                float ov0 = __shfl_xor(hv0, 1);
                float ov1 = __shfl_xor(hv1, 1);
                float ov2 = __shfl_xor(hv2, 1);
                float ov3 = __shfl_xor(hv3, 1);
                bool odd = (l15 & 1);
                float lo0 = odd ? ov2 : hv0,  hi0 = odd ? hv2 : ov0;
                float lo1 = odd ? ov3 : hv1,  hi1 = odd ? hv3 : ov1;
                int col = g*32 + nt*8 + (l15 >> 1);
                int row = h*32 + ms*16 + q*4 + (odd ? 2 : 0);
                sH1[row*68 + col]     = pk_trunc(lo0, hi0);
                sH1[(row+1)*68 + col] = pk_trunc(lo1, hi1);
            }
        }
        __syncthreads();
        #pragma unroll
        for (int sx = 0; sx < 2; ++sx) {
            short8 hfr[4];
            #pragma unroll
            for (int kt = 0; kt < 4; ++kt)
                hfr[kt] = *(const short8*)&sH1[(h*32 + sx*16 + l15)*68 + kt*16 + q*4];
            float part[4] = {0.f, 0.f, 0.f, 0.f};
            #pragma unroll
            for (int nt = 0; nt < 2; ++nt) {
                f32x4 acc = {0.f, 0.f, 0.f, 0.f};
                acc = __builtin_amdgcn_mfma_f32_16x16x32_bf16(hfr[0], w2f[nt][0], acc, 0, 0, 0);
                acc = __builtin_amdgcn_mfma_f32_16x16x32_bf16(hfr[1], w2f[nt][1], acc, 0, 0, 0);
                acc = __builtin_amdgcn_mfma_f32_16x16x32_bf16(hfr[2], w2f[nt][2], acc, 0, 0, 0);
                acc = __builtin_amdgcn_mfma_f32_16x16x32_bf16(hfr[3], w2f[nt][3], acc, 0, 0, 0);
                #pragma unroll
                for (int r = 0; r < 4; ++r) {
                    float hv = acc[r] + t2v[nt];
                    hv = hv > 0.f ? hv : hv*0.01f;
                    part[r] = fmaf(hv, w3v[nt], part[r]);
                }
            }
            #pragma unroll
            for (int r = 0; r < 4; ++r) {
                part[r] += __shfl_xor(part[r], 1);
                part[r] += __shfl_xor(part[r], 2);
                part[r] += __shfl_xor(part[r], 4);
                part[r] += __shfl_xor(part[r], 8);
            }
            if (l15 == 0)
                #pragma unroll
                for (int r = 0; r < 4; ++r)
                    sPart[g][h*32 + sx*16 + q*4 + r] = part[r];
        }
        __syncthreads();
        if (t < 64) {
            float logit = sPart[0][t] + sPart[1][t] + b3v;
            float sg = 1.f / (1.f + __expf(-logit));
            int i = i0 + ch*2 + (t >> 5);
            int j = j0 + (t & 31);
            float epl = (i == j) ? 0.f : ep[((size_t)(b*NPTS + i))*NPTS + j];
            ep_out[((size_t)(b*NPTS + i))*NPTS + j] = sg * epl;
        }
    }
}

// ---- reductions ----
__device__ __forceinline__ float block_reduce_sum512(float v, float* red) {
    #pragma unroll
    for (int off = 32; off; off >>= 1) v += __shfl_down(v, off);
    int wid = threadIdx.x >> 6;
    if ((threadIdx.x & 63) == 0) red[wid] = v;
    __syncthreads();
    float s = ((red[0] + red[1]) + (red[2] + red[3]))
            + ((red[4] + red[5]) + (red[6] + red[7]));
    __syncthreads();
    return s;
}

// ---- finish: mirror (sg,ns lower-tri gather) + topk + L1 renorm + diag + norm
// Gathered elements are always in UPPER parts of other rows (written by mlp,
// never written here) -> no cross-block race. sg_buf/ns upper are L2-resident.
__global__ __launch_bounds__(512)
void finish_kernel(const float* __restrict__ ep_gen, const float* __restrict__ sg_buf,
                   float* __restrict__ ep_out, float* __restrict__ ns_out)
{
    __shared__ __align__(16) float r[NPTS];
    __shared__ float red[8];
    const int row = blockIdx.x;          // b*512 + i
    const int b   = row >> 9;
    const int i   = row & (NPTS - 1);
    const int ti  = i >> 5;
    const int t   = threadIdx.x;         // = j
    const float* gen = &ep_gen[(size_t)row * NPTS];

    const bool lower = (t >> 5) < ti;    // supertile(j) < supertile(i): mirror
    float sg;
    if (lower) {
        sg = sg_buf[((size_t)(b*NPTS + t))*NPTS + i];                  // gather [j][i]
        ns_out[(size_t)row*NPTS + t] = ns_out[((size_t)(b*NPTS + t))*NPTS + i];
    } else {
        sg = sg_buf[(size_t)row*NPTS + t];                             // row read
    }
    float gv = (t == i) ? 0.f : gen[t];
    float v = sg * gv;
    r[t] = v;
    __syncthreads();

    float s_last = block_reduce_sum512(gv, red);

    // rank by strict-greater count; sigmoid*uniform values: exact float ties
    // are measure-zero, index tiebreak cannot change the kept set.
    int c = 0;
    #pragma unroll 4
    for (int k = 0; k < NPTS; k += 4) {
        float4 rv = *(const float4*)&r[k];
        c += (rv.x > v) + (rv.y > v) + (rv.z > v) + (rv.w > v);
    }
    float m = (c < KVAL) ? v : 0.f;

    float l1 = block_reduce_sum512(m, red);
    float scale = s_last / fmaxf(l1, 1e-12f);
    float f = m*scale + ((t == i) ? 1.f : 0.f) + 1e-6f;

    float s2 = block_reduce_sum512(f, red);
    ep_out[(size_t)row*NPTS + t] = f / s2;
}

// ---- fallback topk (reads ep_io written by mlp_full) ----
__global__ __launch_bounds__(512)
void topk_norm_kernel(const float* __restrict__ ep_gen, float* __restrict__ ep_io) {
    __shared__ __align__(16) float r[NPTS];
    __shared__ float red[8];
    const int row = blockIdx.x;
    const int i   = row & (NPTS - 1);
    const int t   = threadIdx.x;
    const float* gen = &ep_gen[(size_t)row * NPTS];
    float* io        = &ep_io [(size_t)row * NPTS];
    float v = io[t];
    r[t] = v;
    float gv = (t == i) ? 0.f : gen[t];
    __syncthreads();
    float s_last = block_reduce_sum512(gv, red);
    int c = 0;
    #pragma unroll 4
    for (int k = 0; k < NPTS; k += 4) {
        float4 rv = *(const float4*)&r[k];
        c += (rv.x > v) + (rv.y > v) + (rv.z > v) + (rv.w > v);
    }
    float m = (c < KVAL) ? v : 0.f;
    float l1 = block_reduce_sum512(m, red);
    float scale = s_last / fmaxf(l1, 1e-12f);
    float f = m*scale + ((t == i) ? 1.f : 0.f) + 1e-6f;
    float s2 = block_reduce_sum512(f, red);
    io[t] = f / s2;
}

extern "C" void kernel_launch(void* const* d_in, const int* in_sizes, int n_in,
                              void* d_out, int out_size, void* d_ws, size_t ws_size,
                              hipStream_t stream) {
    const float* vp  = (const float*)d_in[0];
    const float* ep  = (const float*)d_in[1];
    const float* W1  = (const float*)d_in[2];
    const float* g1  = (const float*)d_in[3];
    const float* be1 = (const float*)d_in[4];
    const float* m1  = (const float*)d_in[5];
    const float* v1  = (const float*)d_in[6];
    const float* W2  = (const float*)d_in[7];
    const float* g2  = (const float*)d_in[8];
    const float* be2 = (const float*)d_in[9];
    const float* m2  = (const float*)d_in[10];
    const float* v2  = (const float*)d_in[11];
    const float* W3  = (const float*)d_in[12];
    const float* b3  = (const float*)d_in[13];

    float* out    = (float*)d_out;
    float* ep_out = out;                          // [2,512,512]
    float* ns_out = out + (size_t)NB*NPTS*NPTS;   // [2,512,512]

    const size_t need = 49152 + (size_t)NB*NPTS*NPTS*sizeof(float);  // 48K frags + 2M sg
    if (ws_size >= need) {
        uint4* wsp    = (uint4*)d_ws;
        float* sg_buf = (float*)((char*)d_ws + 49152);
        prep_weights<<<dim3(12), dim3(256), 0, stream>>>(W1, g1, v1, W2, g2, v2, wsp);
        mlp_tri_kernel<<<dim3(272, NB), dim3(256), 0, stream>>>(
            vp, wsp, g1, be1, m1, v1, g2, be2, m2, v2, W3, b3, ns_out, sg_buf);
        finish_kernel<<<dim3(NB*NPTS), dim3(512), 0, stream>>>(ep, sg_buf, ep_out, ns_out);
    } else {
        mlp_full_kernel<<<dim3(1024, NB), dim3(256), 0, stream>>>(
            vp, ep, W1, g1, be1, m1, v1, W2, g2, be2, m2, v2, W3, b3, ep_out, ns_out);
        topk_norm_kernel<<<dim3(NB*NPTS), dim3(512), 0, stream>>>(ep, ep_out);
    }
}